// Round 4
// baseline (539.197 us; speedup 1.0000x reference)
//
#include <hip/hip_runtime.h>
#include <hip/hip_bf16.h>

#define T_SEQ 512
#define B_BAT 256
#define U_OSC 64
#define ED_ 100
#define PD_ 20
#define NC_ 2
#define NROW (T_SEQ * B_BAT)          // 131072 rows, row = t*256 + b
#define BU_ (B_BAT * U_OSC)           // 16384 chains
#define NVOC 32000
#define DT_C 1e-3f
#define SC_C 0.2f
#define MU_C 1.0f
#define NSTEP 20

typedef float v2f __attribute__((ext_vector_type(2)));

// Workspace: zb[t][b][u][2] interleaved (67.1 MB); then (table path) the
// relu(E@W1cat+b) lookup table tab[32000][128] (16.4 MB).

// ---------------------------------------------------------------------------
// Packed Hopf Euler step:  z' = (-DT*z)*r2 + (C1*z + w),  w = (-dom*zi+dcr,
// dom*zr+dci), r2 = zr^2+zi^2.  Depth-3 chain, 7 insts (4 VOP3P).
// ---------------------------------------------------------------------------
#define HOPF_STEP(z, domv, dcv, c1v, ndtv)                                     \
    {                                                                          \
        v2f w_, u1_, ab_, h_;                                                  \
        asm("v_pk_fma_f32 %0, %1, %2, %3 op_sel:[0,1,0] op_sel_hi:[1,0,1]"     \
            : "=v"(w_) : "v"(domv), "v"(z), "v"(dcv));                         \
        asm("v_pk_mul_f32 %0, %1, %1" : "=v"(u1_) : "v"(z));                   \
        asm("v_pk_mul_f32 %0, %1, %2" : "=v"(ab_) : "v"(ndtv), "v"(z));        \
        asm("v_pk_fma_f32 %0, %1, %2, %3"                                      \
            : "=v"(h_) : "v"(c1v), "v"(z), "v"(w_));                           \
        float r2_ = u1_.x + u1_.y;                                             \
        z.x = fmaf(ab_.x, r2_, h_.x);                                          \
        z.y = fmaf(ab_.y, r2_, h_.y);                                          \
    }

// ---------------------------------------------------------------------------
// K0: tab[v][c] = relu(E[v]@W1cat + b1cat), c interleaved (2u+p). 250 blocks.
// ---------------------------------------------------------------------------
__global__ __launch_bounds__(256) void k0_table(
    const float* __restrict__ E,
    const float* __restrict__ W1r, const float* __restrict__ b1r,
    const float* __restrict__ W1i, const float* __restrict__ b1i,
    float* __restrict__ tab)
{
    __shared__ float embT[128 * 104];
    __shared__ float Wc[100 * 128];
    __shared__ float bias[128];
    const int tid = threadIdx.x;
    const int row0g = blockIdx.x * 128;

    for (int idx = tid; idx < 100 * 128; idx += 256) {
        int k = idx >> 7, c = idx & 127;
        Wc[idx] = (c & 1) ? W1i[k * 64 + (c >> 1)] : W1r[k * 64 + (c >> 1)];
    }
    if (tid < 128) bias[tid] = (tid & 1) ? b1i[tid >> 1] : b1r[tid >> 1];
    {   // stage 128 E rows (400 B each, 16B-aligned)
        int r = tid >> 1, half = tid & 1;
        const float4* src = (const float4*)(E + (size_t)(row0g + r) * ED_);
        float4* dst = (float4*)&embT[r * 104];
        for (int j = half; j < 25; j += 2) dst[j] = src[j];
    }
    __syncthreads();

    const int col0 = (tid & 15) * 8;
    const int row0 = (tid >> 4) * 8;
    float acc[8][8];
#pragma unroll
    for (int i = 0; i < 8; ++i)
#pragma unroll
        for (int j = 0; j < 8; ++j) acc[i][j] = 0.f;

    for (int k0 = 0; k0 < 100; k0 += 4) {
        float ev[8][4];
#pragma unroll
        for (int i = 0; i < 8; ++i)
            *(float4*)ev[i] = *(const float4*)&embT[(row0 + i) * 104 + k0];
#pragma unroll
        for (int kk = 0; kk < 4; ++kk) {
            float4 wA = *(const float4*)&Wc[(k0 + kk) * 128 + col0];
            float4 wB = *(const float4*)&Wc[(k0 + kk) * 128 + col0 + 4];
#pragma unroll
            for (int i = 0; i < 8; ++i) {
                float e = ev[i][kk];
                acc[i][0] = fmaf(e, wA.x, acc[i][0]);
                acc[i][1] = fmaf(e, wA.y, acc[i][1]);
                acc[i][2] = fmaf(e, wA.z, acc[i][2]);
                acc[i][3] = fmaf(e, wA.w, acc[i][3]);
                acc[i][4] = fmaf(e, wB.x, acc[i][4]);
                acc[i][5] = fmaf(e, wB.y, acc[i][5]);
                acc[i][6] = fmaf(e, wB.z, acc[i][6]);
                acc[i][7] = fmaf(e, wB.w, acc[i][7]);
            }
        }
    }
#pragma unroll
    for (int i = 0; i < 8; ++i) {
        float4 o0, o1;
        o0.x = fmaxf(acc[i][0] + bias[col0 + 0], 0.f);
        o0.y = fmaxf(acc[i][1] + bias[col0 + 1], 0.f);
        o0.z = fmaxf(acc[i][2] + bias[col0 + 2], 0.f);
        o0.w = fmaxf(acc[i][3] + bias[col0 + 3], 0.f);
        o1.x = fmaxf(acc[i][4] + bias[col0 + 4], 0.f);
        o1.y = fmaxf(acc[i][5] + bias[col0 + 5], 0.f);
        o1.z = fmaxf(acc[i][6] + bias[col0 + 6], 0.f);
        o1.w = fmaxf(acc[i][7] + bias[col0 + 7], 0.f);
        size_t base = (size_t)(row0g + row0 + i) * 128 + col0;
        *(float4*)&tab[base] = o0;
        *(float4*)&tab[base + 4] = o1;
    }
}

// ---------------------------------------------------------------------------
// Hopf layer 1, forcing gathered from tab[tok]: thread = (b,u); wave = one b
// (token id wave-uniform). Writes z1 to zb. Token ring dist 8, row ring 4.
// ---------------------------------------------------------------------------
__global__ __launch_bounds__(64) void hopf_gather(
    const float* __restrict__ tab, const int* __restrict__ xin,
    float* __restrict__ zb, const float* __restrict__ omega)
{
    const int cid = blockIdx.x * 64 + threadIdx.x;
    const int b = cid >> 6, u = cid & 63;
    const int* xb = xin + b * T_SEQ;
    const float* tabu = tab + 2 * u;
    const size_t TSTR = (size_t)BU_ * 2;
    float* outp = zb + (size_t)cid * 2;

    const float dom = DT_C * omega[u];
    const v2f domv = { -dom, dom };
    const v2f c1v  = { 1.0f + DT_C * MU_C, 1.0f + DT_C * MU_C };
    const v2f ndtv = { -DT_C, -DT_C };
    const float SD = DT_C * SC_C;

    v2f pf[4]; int tkr[4];
#pragma unroll
    for (int j = 0; j < 4; ++j)
        pf[j] = *(const v2f*)(tabu + (size_t)xb[j] * 128);
#pragma unroll
    for (int j = 0; j < 4; ++j) tkr[j] = xb[j + 4];

    v2f z = { 0.1f, 0.0f };
    v2f oz[4];
    for (int t0 = 0; t0 < T_SEQ; t0 += 4) {
#pragma unroll
        for (int j = 0; j < 4; ++j) {
            const int t = t0 + j;
            const v2f f = pf[j];
            pf[j] = *(const v2f*)(tabu + (size_t)tkr[j] * 128);  // row t+4
            const int t8 = (t + 8 < T_SEQ) ? (t + 8) : (T_SEQ - 1);
            tkr[j] = xb[t8];
            const v2f dcv = { SD * f.x, SD * f.y };
#pragma unroll
            for (int s = 0; s < NSTEP; ++s) HOPF_STEP(z, domv, dcv, c1v, ndtv)
            oz[j] = z;
            *(v2f*)(outp + (size_t)t * TSTR) = oz[j];
        }
    }
}

// ---------------------------------------------------------------------------
// Hopf in-place on zb (layer 2; also layer-1 fallback). Prefetch dist 4.
// ---------------------------------------------------------------------------
__global__ __launch_bounds__(64) void hopf_inplace(
    float* zb, const float* __restrict__ omega)
{
    const int cid = blockIdx.x * 64 + threadIdx.x;
    const float dom = DT_C * omega[cid & 63];
    const v2f domv = { -dom, dom };
    const v2f c1v  = { 1.0f + DT_C * MU_C, 1.0f + DT_C * MU_C };
    const v2f ndtv = { -DT_C, -DT_C };
    const float SD = DT_C * SC_C;
    const size_t TSTR = (size_t)BU_ * 2;
    float* base = zb + (size_t)cid * 2;

    v2f pf[4];
#pragma unroll
    for (int j = 0; j < 4; ++j)
        pf[j] = *(const v2f*)(base + (size_t)j * TSTR);

    v2f z = { 0.1f, 0.0f };
    v2f oz[4];
    for (int t0 = 0; t0 < T_SEQ; t0 += 4) {
#pragma unroll
        for (int j = 0; j < 4; ++j) {
            const int t = t0 + j;
            const v2f f = pf[j];
            const int tp = (t + 4 < T_SEQ) ? (t + 4) : (T_SEQ - 1);
            pf[j] = *(const v2f*)(base + (size_t)tp * TSTR);
            const v2f dcv = { SD * f.x, SD * f.y };
#pragma unroll
            for (int s = 0; s < NSTEP; ++s) HOPF_STEP(z, domv, dcv, c1v, ndtv)
            oz[j] = z;
            *(v2f*)(base + (size_t)t * TSTR) = oz[j];
        }
    }
}

// ---------------------------------------------------------------------------
// K1 (fallback only): emb = E[x]; zb = relu(emb@W1cat+b1cat), interleaved.
// ---------------------------------------------------------------------------
__global__ __launch_bounds__(256) void k1_embed_proj(
    const int* __restrict__ xin, const float* __restrict__ E,
    const float* __restrict__ W1r, const float* __restrict__ b1r,
    const float* __restrict__ W1i, const float* __restrict__ b1i,
    float* __restrict__ zb)
{
    __shared__ float embT[128 * 104];
    __shared__ float Wc[100 * 128];
    __shared__ float bias[128];
    const int tid = threadIdx.x;
    const int row0g = blockIdx.x * 128;

    for (int idx = tid; idx < 100 * 128; idx += 256) {
        int k = idx >> 7, c = idx & 127;
        Wc[idx] = (c & 1) ? W1i[k * 64 + (c >> 1)] : W1r[k * 64 + (c >> 1)];
    }
    if (tid < 128) bias[tid] = (tid & 1) ? b1i[tid >> 1] : b1r[tid >> 1];
    {
        int r = tid >> 1, half = tid & 1;
        int rg = row0g + r;
        int t = rg >> 8, b = rg & 255;
        int tok = xin[b * T_SEQ + t];
        const float4* src = (const float4*)(E + (size_t)tok * ED_);
        float4* dst = (float4*)&embT[r * 104];
        for (int j = half; j < 25; j += 2) dst[j] = src[j];
    }
    __syncthreads();

    const int col0 = (tid & 15) * 8;
    const int row0 = (tid >> 4) * 8;
    float acc[8][8];
#pragma unroll
    for (int i = 0; i < 8; ++i)
#pragma unroll
        for (int j = 0; j < 8; ++j) acc[i][j] = 0.f;

    for (int k0 = 0; k0 < 100; k0 += 4) {
        float ev[8][4];
#pragma unroll
        for (int i = 0; i < 8; ++i)
            *(float4*)ev[i] = *(const float4*)&embT[(row0 + i) * 104 + k0];
#pragma unroll
        for (int kk = 0; kk < 4; ++kk) {
            float4 wA = *(const float4*)&Wc[(k0 + kk) * 128 + col0];
            float4 wB = *(const float4*)&Wc[(k0 + kk) * 128 + col0 + 4];
#pragma unroll
            for (int i = 0; i < 8; ++i) {
                float e = ev[i][kk];
                acc[i][0] = fmaf(e, wA.x, acc[i][0]);
                acc[i][1] = fmaf(e, wA.y, acc[i][1]);
                acc[i][2] = fmaf(e, wA.z, acc[i][2]);
                acc[i][3] = fmaf(e, wA.w, acc[i][3]);
                acc[i][4] = fmaf(e, wB.x, acc[i][4]);
                acc[i][5] = fmaf(e, wB.y, acc[i][5]);
                acc[i][6] = fmaf(e, wB.z, acc[i][6]);
                acc[i][7] = fmaf(e, wB.w, acc[i][7]);
            }
        }
    }
#pragma unroll
    for (int i = 0; i < 8; ++i) {
        float4 o0, o1;
        o0.x = fmaxf(acc[i][0] + bias[col0 + 0], 0.f);
        o0.y = fmaxf(acc[i][1] + bias[col0 + 1], 0.f);
        o0.z = fmaxf(acc[i][2] + bias[col0 + 2], 0.f);
        o0.w = fmaxf(acc[i][3] + bias[col0 + 3], 0.f);
        o1.x = fmaxf(acc[i][4] + bias[col0 + 4], 0.f);
        o1.y = fmaxf(acc[i][5] + bias[col0 + 5], 0.f);
        o1.z = fmaxf(acc[i][6] + bias[col0 + 6], 0.f);
        o1.w = fmaxf(acc[i][7] + bias[col0 + 7], 0.f);
        size_t base = (size_t)(row0g + row0 + i) * 128 + col0;
        *(float4*)&zb[base] = o0;
        *(float4*)&zb[base + 4] = o1;
    }
}

// ---------------------------------------------------------------------------
// K3: h1 = relu(zcat@Wp1+bp1); x2 = relu(h1@W2cat+b2cat), in place on zb.
// ---------------------------------------------------------------------------
__global__ __launch_bounds__(256) void k3_mid(
    float* zb,
    const float* __restrict__ Wp1, const float* __restrict__ bp1,
    const float* __restrict__ W2r, const float* __restrict__ b2r,
    const float* __restrict__ W2i, const float* __restrict__ b2i)
{
    __shared__ float zt[128 * 128];
    __shared__ float Wa[128 * 64];
    __shared__ float h1t[128 * 68];
    __shared__ float bp1s[64];
    __shared__ float b2s[128];
    const int tid = threadIdx.x;
    const int row0g = blockIdx.x * 128;

    for (int f = tid; f < 128 * 32; f += 256) {
        int r = f >> 5, c = (f & 31) * 4;
        *(float4*)&zt[r * 128 + c] =
            *(const float4*)&zb[(size_t)(row0g + r) * 128 + c];
    }
    for (int idx = tid; idx < 128 * 64; idx += 256) {
        int kI = idx >> 6, c = idx & 63;
        int kRef = (kI & 1) * 64 + (kI >> 1);
        Wa[idx] = Wp1[kRef * 64 + c];
    }
    if (tid < 64) bp1s[tid] = bp1[tid];
    __syncthreads();

    {
        const int col0 = (tid & 15) * 4;
        const int row0 = (tid >> 4) * 8;
        float acc[8][4];
#pragma unroll
        for (int i = 0; i < 8; ++i)
#pragma unroll
            for (int j = 0; j < 4; ++j) acc[i][j] = 0.f;
        for (int k0 = 0; k0 < 128; k0 += 4) {
            float zv[8][4];
#pragma unroll
            for (int i = 0; i < 8; ++i)
                *(float4*)zv[i] = *(const float4*)&zt[(row0 + i) * 128 + k0];
#pragma unroll
            for (int kk = 0; kk < 4; ++kk) {
                float4 w = *(const float4*)&Wa[(k0 + kk) * 64 + col0];
#pragma unroll
                for (int i = 0; i < 8; ++i) {
                    float z1 = zv[i][kk];
                    acc[i][0] = fmaf(z1, w.x, acc[i][0]);
                    acc[i][1] = fmaf(z1, w.y, acc[i][1]);
                    acc[i][2] = fmaf(z1, w.z, acc[i][2]);
                    acc[i][3] = fmaf(z1, w.w, acc[i][3]);
                }
            }
        }
#pragma unroll
        for (int i = 0; i < 8; ++i) {
            float4 o;
            o.x = fmaxf(acc[i][0] + bp1s[col0 + 0], 0.f);
            o.y = fmaxf(acc[i][1] + bp1s[col0 + 1], 0.f);
            o.z = fmaxf(acc[i][2] + bp1s[col0 + 2], 0.f);
            o.w = fmaxf(acc[i][3] + bp1s[col0 + 3], 0.f);
            *(float4*)&h1t[(row0 + i) * 68 + col0] = o;
        }
    }
    __syncthreads();
    for (int idx = tid; idx < 64 * 128; idx += 256) {
        int k = idx >> 7, c = idx & 127;
        Wa[idx] = (c & 1) ? W2i[k * 64 + (c >> 1)] : W2r[k * 64 + (c >> 1)];
    }
    if (tid < 128) b2s[tid] = (tid & 1) ? b2i[tid >> 1] : b2r[tid >> 1];
    __syncthreads();

    {
        const int col0 = (tid & 15) * 8;
        const int row0 = (tid >> 4) * 8;
        float acc[8][8];
#pragma unroll
        for (int i = 0; i < 8; ++i)
#pragma unroll
            for (int j = 0; j < 8; ++j) acc[i][j] = 0.f;
        for (int k0 = 0; k0 < 64; k0 += 4) {
            float hv[8][4];
#pragma unroll
            for (int i = 0; i < 8; ++i)
                *(float4*)hv[i] = *(const float4*)&h1t[(row0 + i) * 68 + k0];
#pragma unroll
            for (int kk = 0; kk < 4; ++kk) {
                float4 wA = *(const float4*)&Wa[(k0 + kk) * 128 + col0];
                float4 wB = *(const float4*)&Wa[(k0 + kk) * 128 + col0 + 4];
#pragma unroll
                for (int i = 0; i < 8; ++i) {
                    float h = hv[i][kk];
                    acc[i][0] = fmaf(h, wA.x, acc[i][0]);
                    acc[i][1] = fmaf(h, wA.y, acc[i][1]);
                    acc[i][2] = fmaf(h, wA.z, acc[i][2]);
                    acc[i][3] = fmaf(h, wA.w, acc[i][3]);
                    acc[i][4] = fmaf(h, wB.x, acc[i][4]);
                    acc[i][5] = fmaf(h, wB.y, acc[i][5]);
                    acc[i][6] = fmaf(h, wB.z, acc[i][6]);
                    acc[i][7] = fmaf(h, wB.w, acc[i][7]);
                }
            }
        }
#pragma unroll
        for (int i = 0; i < 8; ++i) {
            float4 o0, o1;
            o0.x = fmaxf(acc[i][0] + b2s[col0 + 0], 0.f);
            o0.y = fmaxf(acc[i][1] + b2s[col0 + 1], 0.f);
            o0.z = fmaxf(acc[i][2] + b2s[col0 + 2], 0.f);
            o0.w = fmaxf(acc[i][3] + b2s[col0 + 3], 0.f);
            o1.x = fmaxf(acc[i][4] + b2s[col0 + 4], 0.f);
            o1.y = fmaxf(acc[i][5] + b2s[col0 + 5], 0.f);
            o1.z = fmaxf(acc[i][6] + b2s[col0 + 6], 0.f);
            o1.w = fmaxf(acc[i][7] + b2s[col0 + 7], 0.f);
            size_t base = (size_t)(row0g + row0 + i) * 128 + col0;
            *(float4*)&zb[base] = o0;
            *(float4*)&zb[base + 4] = o1;
        }
    }
}

// ---------------------------------------------------------------------------
// K5: h2 = relu(zcat@Wp2+bp2); h3 = tanh(h2@Wpr+bpr); out = h3@Wh+bh (f32)
// ---------------------------------------------------------------------------
__global__ __launch_bounds__(256) void k5_out(
    const float* __restrict__ zb,
    const float* __restrict__ Wp2, const float* __restrict__ bp2,
    const float* __restrict__ Wpr, const float* __restrict__ bpr,
    const float* __restrict__ Wh,  const float* __restrict__ bh,
    float* __restrict__ out)
{
    __shared__ float zt[128 * 128];
    __shared__ float Wa[128 * 64];
    __shared__ float h2t[128 * 68];
    __shared__ float h3t[128 * 20];
    __shared__ float Wprs[64 * 20];
    __shared__ float bp2s[64];
    __shared__ float bprs[20];
    __shared__ float Whs[40];
    __shared__ float bhs[2];
    const int tid = threadIdx.x;
    const int row0g = blockIdx.x * 128;

    for (int f = tid; f < 128 * 32; f += 256) {
        int r = f >> 5, c = (f & 31) * 4;
        *(float4*)&zt[r * 128 + c] =
            *(const float4*)&zb[(size_t)(row0g + r) * 128 + c];
    }
    for (int idx = tid; idx < 128 * 64; idx += 256) {
        int kI = idx >> 6, c = idx & 63;
        int kRef = (kI & 1) * 64 + (kI >> 1);
        Wa[idx] = Wp2[kRef * 64 + c];
    }
    for (int idx = tid; idx < 64 * 20; idx += 256) Wprs[idx] = Wpr[idx];
    if (tid < 64) bp2s[tid] = bp2[tid];
    if (tid < 20) bprs[tid] = bpr[tid];
    if (tid < 40) Whs[tid] = Wh[tid];
    if (tid < 2)  bhs[tid] = bh[tid];
    __syncthreads();

    {
        const int col0 = (tid & 15) * 4;
        const int row0 = (tid >> 4) * 8;
        float acc[8][4];
#pragma unroll
        for (int i = 0; i < 8; ++i)
#pragma unroll
            for (int j = 0; j < 4; ++j) acc[i][j] = 0.f;
        for (int k0 = 0; k0 < 128; k0 += 4) {
            float zv[8][4];
#pragma unroll
            for (int i = 0; i < 8; ++i)
                *(float4*)zv[i] = *(const float4*)&zt[(row0 + i) * 128 + k0];
#pragma unroll
            for (int kk = 0; kk < 4; ++kk) {
                float4 w = *(const float4*)&Wa[(k0 + kk) * 64 + col0];
#pragma unroll
                for (int i = 0; i < 8; ++i) {
                    float z1 = zv[i][kk];
                    acc[i][0] = fmaf(z1, w.x, acc[i][0]);
                    acc[i][1] = fmaf(z1, w.y, acc[i][1]);
                    acc[i][2] = fmaf(z1, w.z, acc[i][2]);
                    acc[i][3] = fmaf(z1, w.w, acc[i][3]);
                }
            }
        }
#pragma unroll
        for (int i = 0; i < 8; ++i) {
            float4 o;
            o.x = fmaxf(acc[i][0] + bp2s[col0 + 0], 0.f);
            o.y = fmaxf(acc[i][1] + bp2s[col0 + 1], 0.f);
            o.z = fmaxf(acc[i][2] + bp2s[col0 + 2], 0.f);
            o.w = fmaxf(acc[i][3] + bp2s[col0 + 3], 0.f);
            *(float4*)&h2t[(row0 + i) * 68 + col0] = o;
        }
    }
    __syncthreads();

    {
        const int row = tid >> 1;
        const int c0 = (tid & 1) * 10;
        float a3[10];
#pragma unroll
        for (int j = 0; j < 10; ++j) a3[j] = 0.f;
        for (int k = 0; k < 64; ++k) {
            float hv = h2t[row * 68 + k];
#pragma unroll
            for (int j = 0; j < 10; ++j)
                a3[j] = fmaf(hv, Wprs[k * 20 + c0 + j], a3[j]);
        }
#pragma unroll
        for (int j = 0; j < 10; ++j)
            h3t[row * 20 + c0 + j] = tanhf(a3[j] + bprs[c0 + j]);
    }
    __syncthreads();

    {
        const int row = tid >> 1, c = tid & 1;
        float a = bhs[c];
#pragma unroll
        for (int p = 0; p < 20; ++p)
            a = fmaf(h3t[row * 20 + p], Whs[p * 2 + c], a);
        int rg = row0g + row;
        int t = rg >> 8, b = rg & 255;
        out[(size_t)b * (T_SEQ * NC_) + t * NC_ + c] = a;
    }
}

// ---------------------------------------------------------------------------
extern "C" void kernel_launch(void* const* d_in, const int* in_sizes, int n_in,
                              void* d_out, int out_size, void* d_ws, size_t ws_size,
                              hipStream_t stream) {
    const int*   x   = (const int*)  d_in[0];
    const float* E   = (const float*)d_in[1];
    const float* W1r = (const float*)d_in[2];
    const float* b1r = (const float*)d_in[3];
    const float* W1i = (const float*)d_in[4];
    const float* b1i = (const float*)d_in[5];
    const float* om1 = (const float*)d_in[6];
    const float* Wp1 = (const float*)d_in[7];
    const float* bp1 = (const float*)d_in[8];
    const float* W2r = (const float*)d_in[9];
    const float* b2r = (const float*)d_in[10];
    const float* W2i = (const float*)d_in[11];
    const float* b2i = (const float*)d_in[12];
    const float* om2 = (const float*)d_in[13];
    const float* Wp2 = (const float*)d_in[14];
    const float* bp2 = (const float*)d_in[15];
    const float* Wpr = (const float*)d_in[16];
    const float* bpr = (const float*)d_in[17];
    const float* Wh  = (const float*)d_in[18];
    const float* bh  = (const float*)d_in[19];

    float* zb = (float*)d_ws;                    // [T][B][U][2] — 67.1 MB
    const size_t zb_floats = (size_t)NROW * 128;
    const size_t need = (zb_floats + (size_t)NVOC * 128) * sizeof(float);

    if (ws_size >= need) {
        float* tab = zb + zb_floats;             // relu(E@W1cat+b) — 16.4 MB
        k0_table<<<NVOC / 128, 256, 0, stream>>>(E, W1r, b1r, W1i, b1i, tab);
        hopf_gather<<<BU_ / 64, 64, 0, stream>>>(tab, x, zb, om1);
    } else {
        k1_embed_proj<<<NROW / 128, 256, 0, stream>>>(x, E, W1r, b1r, W1i, b1i, zb);
        hopf_inplace<<<BU_ / 64, 64, 0, stream>>>(zb, om1);
    }
    k3_mid<<<NROW / 128, 256, 0, stream>>>(zb, Wp1, bp1, W2r, b2r, W2i, b2i);
    hopf_inplace<<<BU_ / 64, 64, 0, stream>>>(zb, om2);
    k5_out<<<NROW / 128, 256, 0, stream>>>(zb, Wp2, bp2, Wpr, bpr, Wh, bh,
                                           (float*)d_out);
}

// Round 5
// 522.387 us; speedup vs baseline: 1.0322x; 1.0322x over previous
//
#include <hip/hip_runtime.h>

#define T_SEQ 512
#define B_BAT 256
#define ED_ 100
#define NVOC 32000
#define DT_C 1e-3f
#define SC_C 0.2f
#define MU_C 1.0f
#define NSTEP 20
#define CCH 8                 // tokens per pipeline chunk
#define NCH (T_SEQ / CCH)     // 64 chunks
#define NIT (NCH + 6)         // pipeline depth 7 stages

typedef float v2f __attribute__((ext_vector_type(2)));

// ---------------------------------------------------------------------------
// K0: tab[v][c] = relu(E[v] @ W1cat + b1cat), c interleaved (2u+p). 250 blocks.
// ---------------------------------------------------------------------------
__global__ __launch_bounds__(256) void k0_table(
    const float* __restrict__ E,
    const float* __restrict__ W1r, const float* __restrict__ b1r,
    const float* __restrict__ W1i, const float* __restrict__ b1i,
    float* __restrict__ tab)
{
    __shared__ float embT[128 * 104];
    __shared__ float Wc[100 * 128];
    __shared__ float bias[128];
    const int tid = threadIdx.x;
    const int row0g = blockIdx.x * 128;

    for (int idx = tid; idx < 100 * 128; idx += 256) {
        int k = idx >> 7, c = idx & 127;
        Wc[idx] = (c & 1) ? W1i[k * 64 + (c >> 1)] : W1r[k * 64 + (c >> 1)];
    }
    if (tid < 128) bias[tid] = (tid & 1) ? b1i[tid >> 1] : b1r[tid >> 1];
    {
        int r = tid >> 1, half = tid & 1;
        const float4* src = (const float4*)(E + (size_t)(row0g + r) * ED_);
        float4* dst = (float4*)&embT[r * 104];
        for (int j = half; j < 25; j += 2) dst[j] = src[j];
    }
    __syncthreads();

    const int col0 = (tid & 15) * 8;
    const int row0 = (tid >> 4) * 8;
    float acc[8][8];
#pragma unroll
    for (int i = 0; i < 8; ++i)
#pragma unroll
        for (int j = 0; j < 8; ++j) acc[i][j] = 0.f;

    for (int k0 = 0; k0 < 100; k0 += 4) {
        float ev[8][4];
#pragma unroll
        for (int i = 0; i < 8; ++i)
            *(float4*)ev[i] = *(const float4*)&embT[(row0 + i) * 104 + k0];
#pragma unroll
        for (int kk = 0; kk < 4; ++kk) {
            float4 wA = *(const float4*)&Wc[(k0 + kk) * 128 + col0];
            float4 wB = *(const float4*)&Wc[(k0 + kk) * 128 + col0 + 4];
#pragma unroll
            for (int i = 0; i < 8; ++i) {
                float e = ev[i][kk];
                acc[i][0] = fmaf(e, wA.x, acc[i][0]);
                acc[i][1] = fmaf(e, wA.y, acc[i][1]);
                acc[i][2] = fmaf(e, wA.z, acc[i][2]);
                acc[i][3] = fmaf(e, wA.w, acc[i][3]);
                acc[i][4] = fmaf(e, wB.x, acc[i][4]);
                acc[i][5] = fmaf(e, wB.y, acc[i][5]);
                acc[i][6] = fmaf(e, wB.z, acc[i][6]);
                acc[i][7] = fmaf(e, wB.w, acc[i][7]);
            }
        }
    }
#pragma unroll
    for (int i = 0; i < 8; ++i) {
        float4 o0, o1;
        o0.x = fmaxf(acc[i][0] + bias[col0 + 0], 0.f);
        o0.y = fmaxf(acc[i][1] + bias[col0 + 1], 0.f);
        o0.z = fmaxf(acc[i][2] + bias[col0 + 2], 0.f);
        o0.w = fmaxf(acc[i][3] + bias[col0 + 3], 0.f);
        o1.x = fmaxf(acc[i][4] + bias[col0 + 4], 0.f);
        o1.y = fmaxf(acc[i][5] + bias[col0 + 5], 0.f);
        o1.z = fmaxf(acc[i][6] + bias[col0 + 6], 0.f);
        o1.w = fmaxf(acc[i][7] + bias[col0 + 7], 0.f);
        size_t base = (size_t)(row0g + row0 + i) * 128 + col0;
        *(float4*)&tab[base] = o0;
        *(float4*)&tab[base + 4] = o1;
    }
}

// ---------------------------------------------------------------------------
// Fused pipeline: one block per batch element b, 8 waves with fixed roles,
// 7-stage chunk pipeline (chunk = 8 tokens), all intermediates in LDS.
//   W0: hopf1 (forcing from tab[token])         chunk it
//   W2: h1 = relu(z1cat @ Wp1 + bp1)            chunk it-1
//   W4/W5: x2 = relu(h1 @ W2cat + b2cat)        chunk it-2  (W2cat in VGPRs)
//   W1: hopf2 (forcing from x2 ring)            chunk it-3
//   W3: h2 = relu(z2cat @ Wp2 + bp2)            chunk it-4
//   W6/W7: h3 = tanh(h2 @ Wpr + bpr)            chunk it-5
//   W6: out = h3 @ Wh + bh  -> global           chunk it-6
// ---------------------------------------------------------------------------
__global__ __launch_bounds__(512, 1) void donn_pipe(
    const float* __restrict__ tab, const int* __restrict__ xin,
    const float* __restrict__ om1, const float* __restrict__ om2,
    const float* __restrict__ Wp1, const float* __restrict__ bp1,
    const float* __restrict__ W2r, const float* __restrict__ b2r,
    const float* __restrict__ W2i, const float* __restrict__ b2i,
    const float* __restrict__ Wp2, const float* __restrict__ bp2,
    const float* __restrict__ Wpr, const float* __restrict__ bpr,
    const float* __restrict__ Wh,  const float* __restrict__ bh,
    float* __restrict__ out)
{
    __shared__ __align__(16) float Wp1L[128 * 64];   // [kI][c], rows permuted
    __shared__ __align__(16) float Wp2L[128 * 64];
    __shared__ __align__(16) float Wprs[64 * 20];
    __shared__ float Whs[40];
    __shared__ float bp1s[64], bp2s[64], bprs[20], bhs[2];
    __shared__ v2f   b2ps[64];
    __shared__ __align__(16) float z1r_[2][CCH][128];  // interleaved kI rows
    __shared__ __align__(16) float x2r_[2][CCH][128];
    __shared__ __align__(16) float z2r_[2][CCH][128];
    __shared__ __align__(16) float h1b_[2][CCH][64];
    __shared__ __align__(16) float h2b_[2][CCH][64];
    __shared__ float h3b_[2][CCH][20];

    const int tid = threadIdx.x, wid = tid >> 6, lane = tid & 63;
    const int b = blockIdx.x;
    const int* xb = xin + b * T_SEQ;

    // ---- stage weights/biases into LDS (all threads) ----
    for (int idx = tid; idx < 128 * 64; idx += 512) {
        int kI = idx >> 6, c = idx & 63;
        int kR = (kI & 1) * 64 + (kI >> 1);
        Wp1L[idx] = Wp1[kR * 64 + c];
        Wp2L[idx] = Wp2[kR * 64 + c];
    }
    for (int idx = tid; idx < 64 * 20; idx += 512) Wprs[idx] = Wpr[idx];
    if (tid < 64) { bp1s[tid] = bp1[tid]; bp2s[tid] = bp2[tid];
                    b2ps[tid] = (v2f){ b2r[tid], b2i[tid] }; }
    if (tid < 40) Whs[tid] = Wh[tid];
    if (tid < 20) bprs[tid] = bpr[tid];
    if (tid < 2)  bhs[tid]  = bh[tid];

    // ---- role-private state ----
    const float C1 = 1.0f + DT_C * MU_C;
    const float SD = DT_C * SC_C;
    v2f zH = { 0.1f, 0.0f };                 // hopf state (W0 / W1)
    float domH = 0.f;
    if (wid == 0) domH = DT_C * om1[lane];
    if (wid == 1) domH = DT_C * om2[lane];

    v2f pfA[8], pfB[8];                      // W0 forcing prefetch ping-pong
    int4 idA0, idA1, idB0, idB1;             // token-id prefetch
    if (wid == 0) {
        idA0 = *(const int4*)(xb);
        idA1 = *(const int4*)(xb + 4);
        idB0 = *(const int4*)(xb + 8);
        idB1 = *(const int4*)(xb + 12);
        const float* tl = tab + 2 * lane;
        pfA[0] = *(const v2f*)(tl + (size_t)idA0.x * 128);
        pfA[1] = *(const v2f*)(tl + (size_t)idA0.y * 128);
        pfA[2] = *(const v2f*)(tl + (size_t)idA0.z * 128);
        pfA[3] = *(const v2f*)(tl + (size_t)idA0.w * 128);
        pfA[4] = *(const v2f*)(tl + (size_t)idA1.x * 128);
        pfA[5] = *(const v2f*)(tl + (size_t)idA1.y * 128);
        pfA[6] = *(const v2f*)(tl + (size_t)idA1.z * 128);
        pfA[7] = *(const v2f*)(tl + (size_t)idA1.w * 128);
    }
    v2f w2reg[64];                           // W4/W5: (W2r[k][c], W2i[k][c])
    if (wid == 4 || wid == 5) {
#pragma unroll
        for (int k = 0; k < 64; ++k)
            w2reg[k] = (v2f){ W2r[k * 64 + lane], W2i[k * 64 + lane] };
    }
    __syncthreads();

    // hopf1 chunk body (pfC consumed, pfN filled with chunk c+1 via ids n*,
    // ids of chunk c+2 loaded into f*)
    auto h1_chunk = [&](int c, v2f (&pfC)[8], v2f (&pfN)[8],
                        const int4& n0, const int4& n1, int4& f0, int4& f1) {
        const int s = c & 1;
        const float* tl = tab + 2 * lane;
        pfN[0] = *(const v2f*)(tl + (size_t)n0.x * 128);
        pfN[1] = *(const v2f*)(tl + (size_t)n0.y * 128);
        pfN[2] = *(const v2f*)(tl + (size_t)n0.z * 128);
        pfN[3] = *(const v2f*)(tl + (size_t)n0.w * 128);
        pfN[4] = *(const v2f*)(tl + (size_t)n1.x * 128);
        pfN[5] = *(const v2f*)(tl + (size_t)n1.y * 128);
        pfN[6] = *(const v2f*)(tl + (size_t)n1.z * 128);
        pfN[7] = *(const v2f*)(tl + (size_t)n1.w * 128);
        const int cf = (c + 2 < NCH) ? (c + 2) : (NCH - 1);
        f0 = *(const int4*)(xb + cf * 8);
        f1 = *(const int4*)(xb + cf * 8 + 4);
#pragma unroll
        for (int j = 0; j < 8; ++j) {
            const float dcr = SD * pfC[j].x, dci = SD * pfC[j].y;
            float zr = zH.x, zi = zH.y;
#pragma unroll
            for (int st = 0; st < NSTEP; ++st) {
                float wr = fmaf(-domH, zi, dcr);
                float wi = fmaf( domH, zr, dci);
                float r2 = fmaf(zr, zr, zi * zi);
                float g  = fmaf(-DT_C, r2, C1);
                zr = fmaf(g, zr, wr);
                zi = fmaf(g, zi, wi);
            }
            zH.x = zr; zH.y = zi;
            *(v2f*)&z1r_[s][j][2 * lane] = zH;
        }
    };

    for (int it = 0; it < NIT; ++it) {
        if (wid == 0) {                      // hopf1, chunk it
            const int c = it;
            if (c < NCH) {
                if ((c & 1) == 0) h1_chunk(c, pfA, pfB, idB0, idB1, idA0, idA1);
                else              h1_chunk(c, pfB, pfA, idA0, idA1, idB0, idB1);
            }
        } else if (wid == 1) {               // hopf2, chunk it-3
            const int c = it - 3;
            if (0 <= c && c < NCH) {
                const int s = c & 1;
                v2f f[8];
#pragma unroll
                for (int j = 0; j < 8; ++j)
                    f[j] = *(const v2f*)&x2r_[s][j][2 * lane];
#pragma unroll
                for (int j = 0; j < 8; ++j) {
                    const float dcr = SD * f[j].x, dci = SD * f[j].y;
                    float zr = zH.x, zi = zH.y;
#pragma unroll
                    for (int st = 0; st < NSTEP; ++st) {
                        float wr = fmaf(-domH, zi, dcr);
                        float wi = fmaf( domH, zr, dci);
                        float r2 = fmaf(zr, zr, zi * zi);
                        float g  = fmaf(-DT_C, r2, C1);
                        zr = fmaf(g, zr, wr);
                        zi = fmaf(g, zi, wi);
                    }
                    zH.x = zr; zH.y = zi;
                    *(v2f*)&z2r_[s][j][2 * lane] = zH;
                }
            }
        } else if (wid == 2) {               // h1 GEMM, chunk it-1
            const int c = it - 1;
            if (0 <= c && c < NCH) {
                const int s = c & 1;
                float acc[8] = {0,0,0,0,0,0,0,0};
#pragma unroll 4
                for (int kq = 0; kq < 32; ++kq) {
                    float w0 = Wp1L[(4*kq+0)*64 + lane];
                    float w1 = Wp1L[(4*kq+1)*64 + lane];
                    float w2 = Wp1L[(4*kq+2)*64 + lane];
                    float w3 = Wp1L[(4*kq+3)*64 + lane];
#pragma unroll
                    for (int r = 0; r < 8; ++r) {
                        float4 zv = *(const float4*)&z1r_[s][r][4*kq];
                        acc[r] = fmaf(zv.x, w0, acc[r]);
                        acc[r] = fmaf(zv.y, w1, acc[r]);
                        acc[r] = fmaf(zv.z, w2, acc[r]);
                        acc[r] = fmaf(zv.w, w3, acc[r]);
                    }
                }
#pragma unroll
                for (int r = 0; r < 8; ++r)
                    h1b_[s][r][lane] = fmaxf(acc[r] + bp1s[lane], 0.f);
            }
        } else if (wid == 3) {               // h2 GEMM, chunk it-4
            const int c = it - 4;
            if (0 <= c && c < NCH) {
                const int s = c & 1;
                float acc[8] = {0,0,0,0,0,0,0,0};
#pragma unroll 4
                for (int kq = 0; kq < 32; ++kq) {
                    float w0 = Wp2L[(4*kq+0)*64 + lane];
                    float w1 = Wp2L[(4*kq+1)*64 + lane];
                    float w2 = Wp2L[(4*kq+2)*64 + lane];
                    float w3 = Wp2L[(4*kq+3)*64 + lane];
#pragma unroll
                    for (int r = 0; r < 8; ++r) {
                        float4 zv = *(const float4*)&z2r_[s][r][4*kq];
                        acc[r] = fmaf(zv.x, w0, acc[r]);
                        acc[r] = fmaf(zv.y, w1, acc[r]);
                        acc[r] = fmaf(zv.z, w2, acc[r]);
                        acc[r] = fmaf(zv.w, w3, acc[r]);
                    }
                }
#pragma unroll
                for (int r = 0; r < 8; ++r)
                    h2b_[s][r][lane] = fmaxf(acc[r] + bp2s[lane], 0.f);
            }
        } else if (wid == 4 || wid == 5) {   // x2 GEMM, chunk it-2
            const int c = it - 2;
            if (0 <= c && c < NCH) {
                const int s = c & 1;
                const int rb = (wid - 4) * 4;
                v2f a[4] = {{0,0},{0,0},{0,0},{0,0}};
#pragma unroll
                for (int kq = 0; kq < 16; ++kq) {
#pragma unroll
                    for (int r = 0; r < 4; ++r) {
                        float4 hv = *(const float4*)&h1b_[s][rb + r][4*kq];
                        a[r].x = fmaf(hv.x, w2reg[4*kq+0].x, a[r].x);
                        a[r].y = fmaf(hv.x, w2reg[4*kq+0].y, a[r].y);
                        a[r].x = fmaf(hv.y, w2reg[4*kq+1].x, a[r].x);
                        a[r].y = fmaf(hv.y, w2reg[4*kq+1].y, a[r].y);
                        a[r].x = fmaf(hv.z, w2reg[4*kq+2].x, a[r].x);
                        a[r].y = fmaf(hv.z, w2reg[4*kq+2].y, a[r].y);
                        a[r].x = fmaf(hv.w, w2reg[4*kq+3].x, a[r].x);
                        a[r].y = fmaf(hv.w, w2reg[4*kq+3].y, a[r].y);
                    }
                }
#pragma unroll
                for (int r = 0; r < 4; ++r) {
                    v2f o = { fmaxf(a[r].x + b2ps[lane].x, 0.f),
                              fmaxf(a[r].y + b2ps[lane].y, 0.f) };
                    *(v2f*)&x2r_[s][rb + r][2 * lane] = o;
                }
            }
        } else {                             // W6/W7: h3 tanh, chunk it-5
            const int c = it - 5;
            if (0 <= c && c < NCH && lane < 40) {
                const int s = c & 1;
                const int rb = (wid - 6) * 4;
                const int rr = lane / 20, j = lane % 20;
                const int r0 = rb + rr, r1 = rb + rr + 2;
                float a0 = 0.f, a1 = 0.f;
#pragma unroll 4
                for (int k = 0; k < 64; ++k) {
                    float w = Wprs[k * 20 + j];
                    a0 = fmaf(h2b_[s][r0][k], w, a0);
                    a1 = fmaf(h2b_[s][r1][k], w, a1);
                }
                h3b_[s][r0][j] = tanhf(a0 + bprs[j]);
                h3b_[s][r1][j] = tanhf(a1 + bprs[j]);
            }
            if (wid == 6) {                  // logits, chunk it-6
                const int co = it - 6;
                if (0 <= co && co < NCH && lane < 16) {
                    const int s = co & 1;
                    const int r = lane >> 1, cc = lane & 1;
                    float a = bhs[cc];
#pragma unroll
                    for (int p = 0; p < 20; ++p)
                        a = fmaf(h3b_[s][r][p], Whs[p * 2 + cc], a);
                    const int t = co * CCH + r;
                    out[(size_t)b * (T_SEQ * 2) + t * 2 + cc] = a;
                }
            }
        }
        __syncthreads();
    }
}

// ---------------------------------------------------------------------------
extern "C" void kernel_launch(void* const* d_in, const int* in_sizes, int n_in,
                              void* d_out, int out_size, void* d_ws, size_t ws_size,
                              hipStream_t stream) {
    const int*   x   = (const int*)  d_in[0];
    const float* E   = (const float*)d_in[1];
    const float* W1r = (const float*)d_in[2];
    const float* b1r = (const float*)d_in[3];
    const float* W1i = (const float*)d_in[4];
    const float* b1i = (const float*)d_in[5];
    const float* om1 = (const float*)d_in[6];
    const float* Wp1 = (const float*)d_in[7];
    const float* bp1 = (const float*)d_in[8];
    const float* W2r = (const float*)d_in[9];
    const float* b2r = (const float*)d_in[10];
    const float* W2i = (const float*)d_in[11];
    const float* b2i = (const float*)d_in[12];
    const float* om2 = (const float*)d_in[13];
    const float* Wp2 = (const float*)d_in[14];
    const float* bp2 = (const float*)d_in[15];
    const float* Wpr = (const float*)d_in[16];
    const float* bpr = (const float*)d_in[17];
    const float* Wh  = (const float*)d_in[18];
    const float* bh  = (const float*)d_in[19];

    float* tab = (float*)d_ws;   // relu(E@W1cat+b1cat), [32000][128] — 16.4 MB

    k0_table<<<NVOC / 128, 256, 0, stream>>>(E, W1r, b1r, W1i, b1i, tab);
    donn_pipe<<<B_BAT, 512, 0, stream>>>(tab, x, om1, om2,
                                         Wp1, bp1, W2r, b2r, W2i, b2i,
                                         Wp2, bp2, Wpr, bpr, Wh, bh,
                                         (float*)d_out);
}

// Round 6
// 363.985 us; speedup vs baseline: 1.4814x; 1.4352x over previous
//
#include <hip/hip_runtime.h>

#define T_SEQ 512
#define B_BAT 256
#define ED_ 100
#define NVOC 32000
#define DT_C 1e-3f
#define SC_C 0.2f
#define MU_C 1.0f
#define NSTEP 20
#define CCH 8                 // tokens per pipeline chunk
#define NCH (T_SEQ / CCH)     // 64 chunks
#define NIT (NCH + 6)         // pipeline depth 7 stages

typedef float v2f __attribute__((ext_vector_type(2)));

// ---------------------------------------------------------------------------
// K0: tab[v][c] = relu(E[v] @ W1cat + b1cat), c interleaved (2u+p) for the
// per-token v2f gather in W0. 250 blocks.
// ---------------------------------------------------------------------------
__global__ __launch_bounds__(256) void k0_table(
    const float* __restrict__ E,
    const float* __restrict__ W1r, const float* __restrict__ b1r,
    const float* __restrict__ W1i, const float* __restrict__ b1i,
    float* __restrict__ tab)
{
    __shared__ float embT[128 * 104];
    __shared__ float Wc[100 * 128];
    __shared__ float bias[128];
    const int tid = threadIdx.x;
    const int row0g = blockIdx.x * 128;

    for (int idx = tid; idx < 100 * 128; idx += 256) {
        int k = idx >> 7, c = idx & 127;
        Wc[idx] = (c & 1) ? W1i[k * 64 + (c >> 1)] : W1r[k * 64 + (c >> 1)];
    }
    if (tid < 128) bias[tid] = (tid & 1) ? b1i[tid >> 1] : b1r[tid >> 1];
    {
        int r = tid >> 1, half = tid & 1;
        const float4* src = (const float4*)(E + (size_t)(row0g + r) * ED_);
        float4* dst = (float4*)&embT[r * 104];
        for (int j = half; j < 25; j += 2) dst[j] = src[j];
    }
    __syncthreads();

    const int col0 = (tid & 15) * 8;
    const int row0 = (tid >> 4) * 8;
    float acc[8][8];
#pragma unroll
    for (int i = 0; i < 8; ++i)
#pragma unroll
        for (int j = 0; j < 8; ++j) acc[i][j] = 0.f;

    for (int k0 = 0; k0 < 100; k0 += 4) {
        float ev[8][4];
#pragma unroll
        for (int i = 0; i < 8; ++i)
            *(float4*)ev[i] = *(const float4*)&embT[(row0 + i) * 104 + k0];
#pragma unroll
        for (int kk = 0; kk < 4; ++kk) {
            float4 wA = *(const float4*)&Wc[(k0 + kk) * 128 + col0];
            float4 wB = *(const float4*)&Wc[(k0 + kk) * 128 + col0 + 4];
#pragma unroll
            for (int i = 0; i < 8; ++i) {
                float e = ev[i][kk];
                acc[i][0] = fmaf(e, wA.x, acc[i][0]);
                acc[i][1] = fmaf(e, wA.y, acc[i][1]);
                acc[i][2] = fmaf(e, wA.z, acc[i][2]);
                acc[i][3] = fmaf(e, wA.w, acc[i][3]);
                acc[i][4] = fmaf(e, wB.x, acc[i][4]);
                acc[i][5] = fmaf(e, wB.y, acc[i][5]);
                acc[i][6] = fmaf(e, wB.z, acc[i][6]);
                acc[i][7] = fmaf(e, wB.w, acc[i][7]);
            }
        }
    }
#pragma unroll
    for (int i = 0; i < 8; ++i) {
        float4 o0, o1;
        o0.x = fmaxf(acc[i][0] + bias[col0 + 0], 0.f);
        o0.y = fmaxf(acc[i][1] + bias[col0 + 1], 0.f);
        o0.z = fmaxf(acc[i][2] + bias[col0 + 2], 0.f);
        o0.w = fmaxf(acc[i][3] + bias[col0 + 3], 0.f);
        o1.x = fmaxf(acc[i][4] + bias[col0 + 4], 0.f);
        o1.y = fmaxf(acc[i][5] + bias[col0 + 5], 0.f);
        o1.z = fmaxf(acc[i][6] + bias[col0 + 6], 0.f);
        o1.w = fmaxf(acc[i][7] + bias[col0 + 7], 0.f);
        size_t base = (size_t)(row0g + row0 + i) * 128 + col0;
        *(float4*)&tab[base] = o0;
        *(float4*)&tab[base + 4] = o1;
    }
}

// ---------------------------------------------------------------------------
// Fused pipeline, one block per batch element, 8 waves, 7-stage chunk
// pipeline. Ring layout is PLANAR: row[0..63] = r-part, row[64..127] = i-part
// (stride-1 b32 LDS ops, conflict-free; GEMMs consume natural concat order).
// All three 128x64-ish weight matrices live in LDS (no big register arrays ->
// no scratch spill, the round-5 killer).
// ---------------------------------------------------------------------------
__global__ __launch_bounds__(512, 1) void donn_pipe(
    const float* __restrict__ tab, const int* __restrict__ xin,
    const float* __restrict__ om1, const float* __restrict__ om2,
    const float* __restrict__ Wp1, const float* __restrict__ bp1,
    const float* __restrict__ W2r, const float* __restrict__ b2r,
    const float* __restrict__ W2i, const float* __restrict__ b2i,
    const float* __restrict__ Wp2, const float* __restrict__ bp2,
    const float* __restrict__ Wpr, const float* __restrict__ bpr,
    const float* __restrict__ Wh,  const float* __restrict__ bh,
    float* __restrict__ out)
{
    __shared__ __align__(16) float Wp1L[128 * 64];   // [k][c] natural
    __shared__ __align__(16) float Wp2L[128 * 64];
    __shared__ __align__(16) float W2L[64 * 128];    // [k][c] c concat
    __shared__ __align__(16) float Wprs[64 * 20];
    __shared__ float Whs[40];
    __shared__ float bp1s[64], bp2s[64], b2s[128], bprs[20], bhs[2];
    __shared__ __align__(16) float z1r_[2][CCH][128];  // planar r|i
    __shared__ __align__(16) float x2r_[2][CCH][128];
    __shared__ __align__(16) float z2r_[2][CCH][128];
    __shared__ __align__(16) float h1b_[2][CCH][64];
    __shared__ __align__(16) float h2b_[2][CCH][64];
    __shared__ float h3b_[2][CCH][20];

    const int tid = threadIdx.x, wid = tid >> 6, lane = tid & 63;
    const int b = blockIdx.x;
    const int* xb = xin + b * T_SEQ;

    // ---- stage weights/biases into LDS ----
    for (int idx = tid; idx < 128 * 64; idx += 512) {
        Wp1L[idx] = Wp1[idx];
        Wp2L[idx] = Wp2[idx];
    }
    for (int idx = tid; idx < 64 * 128; idx += 512) {
        int k = idx >> 7, c = idx & 127;
        W2L[idx] = (c < 64) ? W2r[k * 64 + c] : W2i[k * 64 + (c - 64)];
    }
    for (int idx = tid; idx < 64 * 20; idx += 512) Wprs[idx] = Wpr[idx];
    if (tid < 64) { bp1s[tid] = bp1[tid]; bp2s[tid] = bp2[tid]; }
    if (tid < 128) b2s[tid] = (tid < 64) ? b2r[tid] : b2i[tid - 64];
    if (tid < 40) Whs[tid] = Wh[tid];
    if (tid < 20) bprs[tid] = bpr[tid];
    if (tid < 2)  bhs[tid]  = bh[tid];

    // ---- role-private state ----
    const float C1 = 1.0f + DT_C * MU_C;
    const float SD = DT_C * SC_C;
    v2f zH = { 0.1f, 0.0f };                 // hopf state (W0 / W1)
    float domH = 0.f;
    if (wid == 0) domH = DT_C * om1[lane];
    if (wid == 1) domH = DT_C * om2[lane];

    v2f pfA[8], pfB[8];                      // W0 forcing prefetch ping-pong
    int4 idA0, idA1, idB0, idB1;
    if (wid == 0) {
        idA0 = *(const int4*)(xb);
        idA1 = *(const int4*)(xb + 4);
        idB0 = *(const int4*)(xb + 8);
        idB1 = *(const int4*)(xb + 12);
        const float* tl = tab + 2 * lane;
        pfA[0] = *(const v2f*)(tl + (size_t)idA0.x * 128);
        pfA[1] = *(const v2f*)(tl + (size_t)idA0.y * 128);
        pfA[2] = *(const v2f*)(tl + (size_t)idA0.z * 128);
        pfA[3] = *(const v2f*)(tl + (size_t)idA0.w * 128);
        pfA[4] = *(const v2f*)(tl + (size_t)idA1.x * 128);
        pfA[5] = *(const v2f*)(tl + (size_t)idA1.y * 128);
        pfA[6] = *(const v2f*)(tl + (size_t)idA1.z * 128);
        pfA[7] = *(const v2f*)(tl + (size_t)idA1.w * 128);
    }
    __syncthreads();

    auto h1_chunk = [&](int c, v2f (&pfC)[8], v2f (&pfN)[8],
                        const int4& n0, const int4& n1, int4& f0, int4& f1) {
        const int s = c & 1;
        const float* tl = tab + 2 * lane;
        pfN[0] = *(const v2f*)(tl + (size_t)n0.x * 128);
        pfN[1] = *(const v2f*)(tl + (size_t)n0.y * 128);
        pfN[2] = *(const v2f*)(tl + (size_t)n0.z * 128);
        pfN[3] = *(const v2f*)(tl + (size_t)n0.w * 128);
        pfN[4] = *(const v2f*)(tl + (size_t)n1.x * 128);
        pfN[5] = *(const v2f*)(tl + (size_t)n1.y * 128);
        pfN[6] = *(const v2f*)(tl + (size_t)n1.z * 128);
        pfN[7] = *(const v2f*)(tl + (size_t)n1.w * 128);
        const int cf = (c + 2 < NCH) ? (c + 2) : (NCH - 1);
        f0 = *(const int4*)(xb + cf * 8);
        f1 = *(const int4*)(xb + cf * 8 + 4);
#pragma unroll
        for (int j = 0; j < 8; ++j) {
            const float dcr = SD * pfC[j].x, dci = SD * pfC[j].y;
            float zr = zH.x, zi = zH.y;
#pragma unroll
            for (int st = 0; st < NSTEP; ++st) {
                float wr = fmaf(-domH, zi, dcr);
                float wi = fmaf( domH, zr, dci);
                float r2 = fmaf(zr, zr, zi * zi);
                float g  = fmaf(-DT_C, r2, C1);
                zr = fmaf(g, zr, wr);
                zi = fmaf(g, zi, wi);
            }
            zH.x = zr; zH.y = zi;
            z1r_[s][j][lane]      = zr;      // planar write, conflict-free
            z1r_[s][j][64 + lane] = zi;
        }
    };

    for (int it = 0; it < NIT; ++it) {
        if (wid == 0) {                      // hopf1, chunk it
            const int c = it;
            if (c < NCH) {
                if ((c & 1) == 0) h1_chunk(c, pfA, pfB, idB0, idB1, idA0, idA1);
                else              h1_chunk(c, pfB, pfA, idA0, idA1, idB0, idB1);
            }
        } else if (wid == 1) {               // hopf2, chunk it-3
            const int c = it - 3;
            if (0 <= c && c < NCH) {
                const int s = c & 1;
                v2f f[8];
#pragma unroll
                for (int j = 0; j < 8; ++j) {
                    f[j].x = x2r_[s][j][lane];
                    f[j].y = x2r_[s][j][64 + lane];
                }
#pragma unroll
                for (int j = 0; j < 8; ++j) {
                    const float dcr = SD * f[j].x, dci = SD * f[j].y;
                    float zr = zH.x, zi = zH.y;
#pragma unroll
                    for (int st = 0; st < NSTEP; ++st) {
                        float wr = fmaf(-domH, zi, dcr);
                        float wi = fmaf( domH, zr, dci);
                        float r2 = fmaf(zr, zr, zi * zi);
                        float g  = fmaf(-DT_C, r2, C1);
                        zr = fmaf(g, zr, wr);
                        zi = fmaf(g, zi, wi);
                    }
                    zH.x = zr; zH.y = zi;
                    z2r_[s][j][lane]      = zr;
                    z2r_[s][j][64 + lane] = zi;
                }
            }
        } else if (wid == 2) {               // h1 GEMM, chunk it-1
            const int c = it - 1;
            if (0 <= c && c < NCH) {
                const int s = c & 1;
                float acc[8] = {0,0,0,0,0,0,0,0};
#pragma unroll 4
                for (int kq = 0; kq < 32; ++kq) {
                    float w0 = Wp1L[(4*kq+0)*64 + lane];
                    float w1 = Wp1L[(4*kq+1)*64 + lane];
                    float w2 = Wp1L[(4*kq+2)*64 + lane];
                    float w3 = Wp1L[(4*kq+3)*64 + lane];
#pragma unroll
                    for (int r = 0; r < 8; ++r) {
                        float4 zv = *(const float4*)&z1r_[s][r][4*kq];
                        acc[r] = fmaf(zv.x, w0, acc[r]);
                        acc[r] = fmaf(zv.y, w1, acc[r]);
                        acc[r] = fmaf(zv.z, w2, acc[r]);
                        acc[r] = fmaf(zv.w, w3, acc[r]);
                    }
                }
#pragma unroll
                for (int r = 0; r < 8; ++r)
                    h1b_[s][r][lane] = fmaxf(acc[r] + bp1s[lane], 0.f);
            }
        } else if (wid == 3) {               // h2 GEMM, chunk it-4
            const int c = it - 4;
            if (0 <= c && c < NCH) {
                const int s = c & 1;
                float acc[8] = {0,0,0,0,0,0,0,0};
#pragma unroll 4
                for (int kq = 0; kq < 32; ++kq) {
                    float w0 = Wp2L[(4*kq+0)*64 + lane];
                    float w1 = Wp2L[(4*kq+1)*64 + lane];
                    float w2 = Wp2L[(4*kq+2)*64 + lane];
                    float w3 = Wp2L[(4*kq+3)*64 + lane];
#pragma unroll
                    for (int r = 0; r < 8; ++r) {
                        float4 zv = *(const float4*)&z2r_[s][r][4*kq];
                        acc[r] = fmaf(zv.x, w0, acc[r]);
                        acc[r] = fmaf(zv.y, w1, acc[r]);
                        acc[r] = fmaf(zv.z, w2, acc[r]);
                        acc[r] = fmaf(zv.w, w3, acc[r]);
                    }
                }
#pragma unroll
                for (int r = 0; r < 8; ++r)
                    h2b_[s][r][lane] = fmaxf(acc[r] + bp2s[lane], 0.f);
            }
        } else if (wid == 4 || wid == 5) {   // x2 GEMM, chunk it-2 (W2L in LDS)
            const int c = it - 2;
            if (0 <= c && c < NCH) {
                const int s = c & 1;
                const int rb = (wid - 4) * 4;
                float ar[4] = {0,0,0,0}, ai[4] = {0,0,0,0};
#pragma unroll 4
                for (int kq = 0; kq < 16; ++kq) {
                    float wr0 = W2L[(4*kq+0)*128 + lane];
                    float wi0 = W2L[(4*kq+0)*128 + 64 + lane];
                    float wr1 = W2L[(4*kq+1)*128 + lane];
                    float wi1 = W2L[(4*kq+1)*128 + 64 + lane];
                    float wr2 = W2L[(4*kq+2)*128 + lane];
                    float wi2 = W2L[(4*kq+2)*128 + 64 + lane];
                    float wr3 = W2L[(4*kq+3)*128 + lane];
                    float wi3 = W2L[(4*kq+3)*128 + 64 + lane];
#pragma unroll
                    for (int r = 0; r < 4; ++r) {
                        float4 hv = *(const float4*)&h1b_[s][rb + r][4*kq];
                        ar[r] = fmaf(hv.x, wr0, ar[r]);
                        ai[r] = fmaf(hv.x, wi0, ai[r]);
                        ar[r] = fmaf(hv.y, wr1, ar[r]);
                        ai[r] = fmaf(hv.y, wi1, ai[r]);
                        ar[r] = fmaf(hv.z, wr2, ar[r]);
                        ai[r] = fmaf(hv.z, wi2, ai[r]);
                        ar[r] = fmaf(hv.w, wr3, ar[r]);
                        ai[r] = fmaf(hv.w, wi3, ai[r]);
                    }
                }
#pragma unroll
                for (int r = 0; r < 4; ++r) {
                    x2r_[s][rb + r][lane]      = fmaxf(ar[r] + b2s[lane], 0.f);
                    x2r_[s][rb + r][64 + lane] = fmaxf(ai[r] + b2s[64 + lane], 0.f);
                }
            }
        } else {                             // W6/W7: h3 tanh, chunk it-5
            const int c = it - 5;
            if (0 <= c && c < NCH && lane < 40) {
                const int s = c & 1;
                const int rb = (wid - 6) * 4;
                const int rr = lane / 20, j = lane % 20;
                const int r0 = rb + rr, r1 = rb + rr + 2;
                float a0 = 0.f, a1 = 0.f;
#pragma unroll 4
                for (int k = 0; k < 64; ++k) {
                    float w = Wprs[k * 20 + j];
                    a0 = fmaf(h2b_[s][r0][k], w, a0);
                    a1 = fmaf(h2b_[s][r1][k], w, a1);
                }
                h3b_[s][r0][j] = tanhf(a0 + bprs[j]);
                h3b_[s][r1][j] = tanhf(a1 + bprs[j]);
            }
            if (wid == 6) {                  // logits, chunk it-6
                const int co = it - 6;
                if (0 <= co && co < NCH && lane < 16) {
                    const int s = co & 1;
                    const int r = lane >> 1, cc = lane & 1;
                    float a = bhs[cc];
#pragma unroll
                    for (int p = 0; p < 20; ++p)
                        a = fmaf(h3b_[s][r][p], Whs[p * 2 + cc], a);
                    const int t = co * CCH + r;
                    out[(size_t)b * (T_SEQ * 2) + t * 2 + cc] = a;
                }
            }
        }
        __syncthreads();
    }
}

// ---------------------------------------------------------------------------
extern "C" void kernel_launch(void* const* d_in, const int* in_sizes, int n_in,
                              void* d_out, int out_size, void* d_ws, size_t ws_size,
                              hipStream_t stream) {
    const int*   x   = (const int*)  d_in[0];
    const float* E   = (const float*)d_in[1];
    const float* W1r = (const float*)d_in[2];
    const float* b1r = (const float*)d_in[3];
    const float* W1i = (const float*)d_in[4];
    const float* b1i = (const float*)d_in[5];
    const float* om1 = (const float*)d_in[6];
    const float* Wp1 = (const float*)d_in[7];
    const float* bp1 = (const float*)d_in[8];
    const float* W2r = (const float*)d_in[9];
    const float* b2r = (const float*)d_in[10];
    const float* W2i = (const float*)d_in[11];
    const float* b2i = (const float*)d_in[12];
    const float* om2 = (const float*)d_in[13];
    const float* Wp2 = (const float*)d_in[14];
    const float* bp2 = (const float*)d_in[15];
    const float* Wpr = (const float*)d_in[16];
    const float* bpr = (const float*)d_in[17];
    const float* Wh  = (const float*)d_in[18];
    const float* bh  = (const float*)d_in[19];

    float* tab = (float*)d_ws;   // relu(E@W1cat+b1cat), [32000][128] — 16.4 MB

    k0_table<<<NVOC / 128, 256, 0, stream>>>(E, W1r, b1r, W1i, b1i, tab);
    donn_pipe<<<B_BAT, 512, 0, stream>>>(tab, x, om1, om2,
                                         Wp1, bp1, W2r, b2r, W2i, b2i,
                                         Wp2, bp2, Wpr, bpr, Wh, bh,
                                         (float*)d_out);
}